// Round 9
// baseline (6334.565 us; speedup 1.0000x reference)
//
#include <hip/hip_runtime.h>
#include <hip/hip_bf16.h>

typedef __attribute__((ext_vector_type(8))) _Float16 half8;
typedef __attribute__((ext_vector_type(4))) float floatx4;
typedef __attribute__((ext_vector_type(4))) unsigned uintx4;

#define NTS 512    // timesteps
#define NB  64     // batch
#define NI  256    // input dim
#define NH  512    // hidden
#define NWG 64     // 4 batch groups x 16 col groups
#define NTHR 512   // 8 waves

#define LOSCALE 4096.0f
#define LOINV   (1.0f / 4096.0f)

// fp32 -> (hi f16, lo f16 scaled by 2^12)
static __device__ __forceinline__ void split8s(const float* p, half8& hi, half8& lo) {
  float4 a = *(const float4*)p;
  float4 b = *(const float4*)(p + 4);
  float v[8] = {a.x, a.y, a.z, a.w, b.x, b.y, b.z, b.w};
#pragma unroll
  for (int i = 0; i < 8; ++i) {
    _Float16 h = (_Float16)v[i];
    hi[i] = h;
    lo[i] = (_Float16)((v[i] - (float)h) * LOSCALE);
  }
}

// pack one h cell with a 2-bit epoch stolen from the lo-plane mantissa LSBs:
// bits[15:0] = hi(f16); bits[31:18] = lo[15:2]; bits[17:16] = epoch.
static __device__ __forceinline__ unsigned pack_cell_e(float v, unsigned ep) {
  _Float16 h = (_Float16)v;
  _Float16 l = (_Float16)((v - (float)h) * LOSCALE);
  union { _Float16 f; unsigned short s; } uh, ul;
  uh.f = h; ul.f = l;
  unsigned lo = ((unsigned)ul.s & 0xFFFCu) | (ep & 3u);
  return (lo << 16) | (unsigned)uh.s;
}

// Coherent 16B load/store: sc0+sc1 = at the device coherence point.
static __device__ __forceinline__ uintx4 load_cx4(const unsigned* p) {
  uintx4 r;
  asm volatile("global_load_dwordx4 %0, %1, off sc0 sc1"
               : "=v"(r)
               : "v"((unsigned long long)p)
               : "memory");
  return r;
}
static __device__ __forceinline__ void store_cx4(unsigned* p, uintx4 v) {
  asm volatile("global_store_dwordx4 %0, %1, off sc0 sc1"
               :: "v"((unsigned long long)p), "v"(v)
               : "memory");
}

// Persistent LSTM v14 = v11 (64 WGs x 8 waves, correctness-verified at 6326us)
// with the ONE fix that matters: __launch_bounds__(512, 1) instead of (512, 2).
// v11's min-2-waves/EU bound capped VGPRs at 128 while the kernel holds ~230
// (weights 132 + accs 36 + in-flight stage 16 + temps) -> total spill-to-scratch
// on the MFMA critical path (VGPR_Count=128, FETCH +165MB, 2x regression).
// A 512-thread block is 2 waves/SIMD, schedulable up to 256 VGPR/wave (m69),
// so cap 256 removes the spill while keeping the structural wins untested in
// v11: coherent stage transactions halved (131K vs 262K dwordx4/step), sync
// partners halved (16 vs 32), publish vectorized (dwordx4), 2 waves/SIMD
// interleave poll with compute. Epoch-in-data protocol unchanged (v9/v10).
// NO mirror/relay machinery (v12/v13 arc aborted the GPU process - abandoned).
__global__ void __launch_bounds__(NTHR, 1) lstm_persist_v14(
    const float* __restrict__ x,     // [512][64][256] fp32
    const float* __restrict__ h0,    // [64][512] fp32
    const float* __restrict__ c0,    // [64][512] fp32
    const float* __restrict__ w_ih,  // [2048][256] fp32
    const float* __restrict__ w_hh,  // [2048][512] fp32
    const float* __restrict__ b_ih,  // [2048] fp32
    const float* __restrict__ b_hh,  // [2048] fp32
    float* __restrict__ out,         // [512][64][512] ++ h_f ++ c_f (fp32)
    unsigned* __restrict__ hbuf)     // [2][64][512] packed u32 cells
{
  const int wg   = blockIdx.x;
  const int mh   = wg >> 4;        // batch quarter (group), 0..3
  const int ng   = wg & 15;        // hidden-col group (32 cols), 0..15
  const int b0   = mh * 16;
  const int j0   = ng * 32;
  const int tid  = threadIdx.x;
  const int wv   = tid >> 6;       // wave 0..7: owns cols j0+4*wv .. +3 (all 4 gates)
  const int lane = tid & 63;
  const int ln   = lane & 15;
  const int lq   = lane >> 4;
  const int gL   = ln >> 2;        // this lane's gate (B-frag row group)
  const int cL   = ln & 3;         // this lane's column within the wave's 4

  // LDS: whh lo-planes s=0..14 (s=15 lives in VGPR) + swizzled h staging tile.
  // hstage quads are XOR-swizzled (slot = qidx ^ (row&7)) on BOTH write and
  // read -> b128 8-lane/slot floor with zero padding. 122880+32768 = 155648 B.
  __shared__ uintx4    wlo[8][15][64];
  __shared__ unsigned  hstage[16][512];

  // ---- EMPIRICAL layout probe: local row of each acc slot (row = 4*lq + r) ----
  int row_l[4];
  {
    half8 ones, rowv;
#pragma unroll
    for (int i = 0; i < 8; ++i) { ones[i] = (_Float16)1.0f; rowv[i] = (_Float16)(float)ln; }
    floatx4 z = {0.f, 0.f, 0.f, 0.f};
    floatx4 p1 = __builtin_amdgcn_mfma_f32_16x16x32_f16(rowv, ones, z, 0, 0, 0);
#pragma unroll
    for (int r = 0; r < 4; ++r)
      row_l[r] = (int)(p1[r] * (1.0f / 32.0f) + 0.5f);
  }

  // ---- weights: hi-planes + wih-lo + whh-lo[15] -> VGPRs; whh-lo[0..14] -> LDS ----
  const int jg   = j0 + wv * 4 + cL;   // this lane's output column
  const int jb   = j0 + wv * 4;        // wave's column base
  const int grow = gL * NH + jg;       // row in w_ih/w_hh
  half8 whh_hi[16], wih_hi[8], wih_lo[8], whh_lo15;
  {
#pragma unroll
    for (int s = 0; s < 16; ++s) {
      half8 lo;
      split8s(w_hh + (size_t)grow * NH + 32 * s + 8 * lq, whh_hi[s], lo);
      if (s < 15) {
        union { half8 h; uintx4 u; } cv; cv.h = lo;
        wlo[wv][s][lane] = cv.u;
      } else {
        whh_lo15 = lo;
      }
    }
#pragma unroll
    for (int s = 0; s < 8; ++s)
      split8s(w_ih + (size_t)grow * NI + 32 * s + 8 * lq, wih_hi[s], wih_lo[s]);
  }

  // ---- per-lane cell state: 4 cells (b = b0+row_l[r], col = jg) ----
  const float bias_i = b_ih[jg]          + b_hh[jg];
  const float bias_f = b_ih[NH + jg]     + b_hh[NH + jg];
  const float bias_g = b_ih[2 * NH + jg] + b_hh[2 * NH + jg];
  const float bias_o = b_ih[3 * NH + jg] + b_hh[3 * NH + jg];

  int   bg_r[4];
  float c_s[4];
#pragma unroll
  for (int r = 0; r < 4; ++r) {
    bg_r[r] = b0 + row_l[r];
    c_s[r]  = c0[bg_r[r] * NH + jg];
  }
  // row this lane stores after the 4x4 transpose (select, not runtime-indexed)
  const int brow_st = b0 + ((cL == 0) ? row_l[0] : (cL == 1) ? row_l[1]
                           : (cL == 2) ? row_l[2] : row_l[3]);

  const int PAR = NB * NH;

  // ---- publish packed h0 (epoch 0) into parity 0 (one-time, scalar) ----
  if (gL == 0) {
#pragma unroll
    for (int r = 0; r < 4; ++r)
      __hip_atomic_store(&hbuf[bg_r[r] * NH + jg], pack_cell_e(h0[bg_r[r] * NH + jg], 0u),
                         __ATOMIC_RELAXED, __HIP_MEMORY_SCOPE_AGENT);
  }

  const int arow  = b0 + ln;          // A-fragment batch row
  const int srow  = tid & 15;         // staging: batch row
  const int qbase = (tid >> 4) * 4;   // staging: first quad index (4 quads/thread)

  for (int t = 0; t < NTS; ++t) {
    // ---- A) issue stage loads for h_t immediately (flight hides under x-part) ----
    const unsigned* hb = hbuf + (t & 1) * PAR + (b0 + srow) * NH + qbase * 4;
    uintx4 hv[4];
#pragma unroll
    for (int q = 0; q < 4; ++q) hv[q] = load_cx4(hb + 4 * q);

    // ---- B) x-part: h-independent ----
    floatx4 acc_x   = {0.f, 0.f, 0.f, 0.f};
    floatx4 accl_x1 = {0.f, 0.f, 0.f, 0.f};
    floatx4 accl_x2 = {0.f, 0.f, 0.f, 0.f};
#pragma unroll
    for (int s = 0; s < 8; ++s) {
      half8 xh, xl;
      split8s(x + ((size_t)t * NB + arow) * NI + 32 * s + 8 * lq, xh, xl);
      acc_x   = __builtin_amdgcn_mfma_f32_16x16x32_f16(xh, wih_hi[s], acc_x,   0, 0, 0);
      accl_x1 = __builtin_amdgcn_mfma_f32_16x16x32_f16(xl, wih_hi[s], accl_x1, 0, 0, 0);
      accl_x2 = __builtin_amdgcn_mfma_f32_16x16x32_f16(xh, wih_lo[s], accl_x2, 0, 0, 0);
    }

    // ---- C) barrier: prior-step hstage readers done ----
    __syncthreads();

    // ---- D) poll+stage: barrier-free per-wave epoch polling, 4 quads/thread ----
    {
      const unsigned em = (unsigned)((t >> 1) & 3) << 16;
      unsigned pend = 0xFu;
      for (;;) {
        asm volatile("s_waitcnt vmcnt(0)" ::: "memory");
#pragma unroll
        for (int q = 0; q < 4; ++q) {
          if (pend & (1u << q)) {
            uintx4 v = hv[q];
            unsigned bad = ((v[0] ^ em) | (v[1] ^ em) | (v[2] ^ em) | (v[3] ^ em))
                           & 0x00030000u;
            if (!bad) {
              const int slot = (qbase + q) ^ (srow & 7);
              *(uintx4*)&hstage[srow][slot << 2] = v;
              pend &= ~(1u << q);
            }
          }
        }
        if (__ballot(pend != 0u) == 0ull) break;
#pragma unroll
        for (int q = 0; q < 4; ++q)
          if (pend & (1u << q)) hv[q] = load_cx4(hb + 4 * q);
      }
    }
    __syncthreads();     // all stage writes visible to all waves

    // ---- E) h-part: gates += h_t*Whh^T; 6 independent 8-deep MFMA chains ----
    floatx4 acc_h  = {0.f, 0.f, 0.f, 0.f}, acc_h2  = {0.f, 0.f, 0.f, 0.f};
    floatx4 accl_a = {0.f, 0.f, 0.f, 0.f}, accl_a2 = {0.f, 0.f, 0.f, 0.f};
    floatx4 accl_b = {0.f, 0.f, 0.f, 0.f}, accl_b2 = {0.f, 0.f, 0.f, 0.f};
#pragma unroll
    for (int s = 0; s < 16; ++s) {
      const int q0 = 8 * s + 2 * lq;
      uintx4 hA = *(const uintx4*)&hstage[ln][(q0 ^ (ln & 7)) << 2];
      uintx4 hB = *(const uintx4*)&hstage[ln][((q0 + 1) ^ (ln & 7)) << 2];
      union { unsigned u[4]; half8 h; } Ah, Al;
      Ah.u[0] = __builtin_amdgcn_perm(hA[1], hA[0], 0x05040100u);
      Al.u[0] = __builtin_amdgcn_perm(hA[1], hA[0], 0x07060302u);
      Ah.u[1] = __builtin_amdgcn_perm(hA[3], hA[2], 0x05040100u);
      Al.u[1] = __builtin_amdgcn_perm(hA[3], hA[2], 0x07060302u);
      Ah.u[2] = __builtin_amdgcn_perm(hB[1], hB[0], 0x05040100u);
      Al.u[2] = __builtin_amdgcn_perm(hB[1], hB[0], 0x07060302u);
      Ah.u[3] = __builtin_amdgcn_perm(hB[3], hB[2], 0x05040100u);
      Al.u[3] = __builtin_amdgcn_perm(hB[3], hB[2], 0x07060302u);
      half8 wlh;
      if (s < 15) {
        union { uintx4 u; half8 h; } wl; wl.u = wlo[wv][s][lane];
        wlh = wl.h;
      } else {
        wlh = whh_lo15;
      }
      if (s < 8) {
        acc_h  = __builtin_amdgcn_mfma_f32_16x16x32_f16(Ah.h, whh_hi[s], acc_h,  0, 0, 0);
        accl_a = __builtin_amdgcn_mfma_f32_16x16x32_f16(Al.h, whh_hi[s], accl_a, 0, 0, 0);
        accl_b = __builtin_amdgcn_mfma_f32_16x16x32_f16(Ah.h, wlh,       accl_b, 0, 0, 0);
      } else {
        acc_h2  = __builtin_amdgcn_mfma_f32_16x16x32_f16(Ah.h, whh_hi[s], acc_h2,  0, 0, 0);
        accl_a2 = __builtin_amdgcn_mfma_f32_16x16x32_f16(Al.h, whh_hi[s], accl_a2, 0, 0, 0);
        accl_b2 = __builtin_amdgcn_mfma_f32_16x16x32_f16(Ah.h, wlh,       accl_b2, 0, 0, 0);
      }
    }

    // ---- F) pointwise LSTM cell: gather i/f/g/o across the 4 gate lane-groups ----
    const int par1 = ((t + 1) & 1) * PAR;
    const unsigned ep1 = (unsigned)(((t + 1) >> 1) & 3);
    float hn[4];
#pragma unroll
    for (int r = 0; r < 4; ++r) {
      float hi_s = acc_x[r] + acc_h[r] + acc_h2[r];
      float lo_s = accl_x1[r] + accl_x2[r] + accl_a[r] + accl_a2[r]
                 + accl_b[r] + accl_b2[r];
      float pre = hi_s + lo_s * LOINV;
      float pb = __shfl_xor(pre, 4);   // value from gate gL^1
      float pc = __shfl_xor(pre, 8);   // value from gate gL^2
      float pd = __shfl_xor(pb, 8);    // value from gate gL^3
      const bool g1 = (gL & 1), g2 = (gL & 2) != 0;
      float xi = g2 ? (g1 ? pd : pc) : (g1 ? pb : pre);
      float xf = g2 ? (g1 ? pc : pd) : (g1 ? pre : pb);
      float xg = g2 ? (g1 ? pb : pre) : (g1 ? pd : pc);
      float xo = g2 ? (g1 ? pre : pb) : (g1 ? pc : pd);
      xi += bias_i; xf += bias_f; xg += bias_g; xo += bias_o;
      float ig = 1.f / (1.f + __expf(-xi));
      float fg = 1.f / (1.f + __expf(-xf));
      float gg = 2.f / (1.f + __expf(-2.f * xg)) - 1.f;   // tanh
      float og = 1.f / (1.f + __expf(-xo));
      c_s[r] = fg * c_s[r] + ig * gg;
      float tc = 2.f / (1.f + __expf(-2.f * c_s[r])) - 1.f;  // tanh(c)
      hn[r] = og * tc;
    }

    if (t < NTS - 1) {
      // ---- G) 4x4 lane transpose (xor 1 then xor 2): lane cL ends up with row
      //      bg_r[cL], cols jb..jb+3 -> ONE dwordx4 publish ----
      const bool c0b = (lane & 1), c1b = (lane & 2) != 0;
      float a0 = __shfl_xor(hn[1], 1), a1 = __shfl_xor(hn[0], 1);
      float a2 = __shfl_xor(hn[3], 1), a3 = __shfl_xor(hn[2], 1);
      float v10 = c0b ? a0 : hn[0], v11 = c0b ? hn[1] : a1;
      float v12 = c0b ? a2 : hn[2], v13 = c0b ? hn[3] : a3;
      float b0v = __shfl_xor(v12, 2), b1v = __shfl_xor(v13, 2);
      float b2v = __shfl_xor(v10, 2), b3v = __shfl_xor(v11, 2);
      float T0 = c1b ? b0v : v10, T1 = c1b ? b1v : v11;
      float T2 = c1b ? v12 : b2v, T3 = c1b ? v13 : b3v;

      if (gL == 0) {
        uintx4 pk;
        pk[0] = pack_cell_e(T0, ep1);
        pk[1] = pack_cell_e(T1, ep1);
        pk[2] = pack_cell_e(T2, ep1);
        pk[3] = pack_cell_e(T3, ep1);
        store_cx4(&hbuf[par1 + brow_st * NH + jb], pk);     // publish FIRST
        floatx4 ov = {T0, T1, T2, T3};
        *(floatx4*)&out[((size_t)t * NB + brow_st) * NH + jb] = ov;
      }
    } else {
      if (gL == 0) {
        const size_t hf_off = (size_t)NTS * NB * NH;
#pragma unroll
        for (int r = 0; r < 4; ++r) {
          out[((size_t)t * NB + bg_r[r]) * NH + jg] = hn[r];
          out[hf_off + bg_r[r] * NH + jg] = hn[r];                          // h_f
          out[hf_off + (size_t)NB * NH + bg_r[r] * NH + jg] = c_s[r];       // c_f
        }
      }
    }
  }
}

extern "C" void kernel_launch(void* const* d_in, const int* in_sizes, int n_in,
                              void* d_out, int out_size, void* d_ws, size_t ws_size,
                              hipStream_t stream) {
  const float* x    = (const float*)d_in[0];
  const float* h0   = (const float*)d_in[1];
  const float* c0   = (const float*)d_in[2];
  const float* w_ih = (const float*)d_in[3];
  const float* w_hh = (const float*)d_in[4];
  const float* b_ih = (const float*)d_in[5];
  const float* b_hh = (const float*)d_in[6];
  float* out = (float*)d_out;
  unsigned* hbuf = (unsigned*)d_ws;   // 2*64*512 u32 = 256 KB

  // 0xAA poison decodes to epoch 2 != E(0)=0: no workspace init needed.
  hipLaunchKernelGGL(lstm_persist_v14, dim3(NWG), dim3(NTHR), 0, stream,
                     x, h0, c0, w_ih, w_hh, b_ih, b_hh, out, hbuf);
}

// Round 11
// 4909.980 us; speedup vs baseline: 1.2901x; 1.2901x over previous
//
#include <hip/hip_runtime.h>
#include <hip/hip_bf16.h>

typedef __attribute__((ext_vector_type(8))) _Float16 half8;
typedef __attribute__((ext_vector_type(4))) float floatx4;
typedef __attribute__((ext_vector_type(4))) unsigned uintx4;

#define NTS 512    // timesteps
#define NB  64     // batch
#define NI  256    // input dim
#define NH  512    // hidden
#define NWG 128    // 4 batch groups x 32 col groups
#define NTHR 256   // 4 waves

#define LOSCALE 4096.0f
#define LOINV   (1.0f / 4096.0f)

// fp32 -> (hi f16, lo f16 scaled by 2^12)
static __device__ __forceinline__ void split8s(const float* p, half8& hi, half8& lo) {
  float4 a = *(const float4*)p;
  float4 b = *(const float4*)(p + 4);
  float v[8] = {a.x, a.y, a.z, a.w, b.x, b.y, b.z, b.w};
#pragma unroll
  for (int i = 0; i < 8; ++i) {
    _Float16 h = (_Float16)v[i];
    hi[i] = h;
    lo[i] = (_Float16)((v[i] - (float)h) * LOSCALE);
  }
}

// pack one h cell with a 2-bit epoch stolen from the lo-plane mantissa LSBs:
// bits[15:0] = hi(f16); bits[31:18] = lo[15:2]; bits[17:16] = epoch.
static __device__ __forceinline__ unsigned pack_cell_e(float v, unsigned ep) {
  _Float16 h = (_Float16)v;
  _Float16 l = (_Float16)((v - (float)h) * LOSCALE);
  union { _Float16 f; unsigned short s; } uh, ul;
  uh.f = h; ul.f = l;
  unsigned lo = ((unsigned)ul.s & 0xFFFCu) | (ep & 3u);
  return (lo << 16) | (unsigned)uh.s;
}

// Coherent 16B load/store: sc0+sc1 = at the device coherence point.
static __device__ __forceinline__ uintx4 load_cx4(const unsigned* p) {
  uintx4 r;
  asm volatile("global_load_dwordx4 %0, %1, off sc0 sc1"
               : "=v"(r)
               : "v"((unsigned long long)p)
               : "memory");
  return r;
}
static __device__ __forceinline__ void store_cx4(unsigned* p, uintx4 v) {
  asm volatile("global_store_dwordx4 %0, %1, off sc0 sc1"
               :: "v"((unsigned long long)p), "v"(v)
               : "memory");
}

// Persistent LSTM v16 = v15 hardened. v15's 2-deep pipelined poll could exit
// the loop with 8 loads still in flight; the compiler models an inline-asm
// load's register write as complete at ISSUE, so it may reuse those registers
// before any drain -> a late completion clobbers a live value (and on odd
// steps em(t)==em(t-1), so an accounting slip could false-accept other-parity
// register residue). v16 drains vmcnt(0) explicitly BEFORE every loop exit;
// the in-loop pipelined alternation (vmcnt(8)) is unchanged, so the round-
// latency halving mechanism survives. v10 had no such window (it waited
// vmcnt(0) every round), which is consistent with v10 passing and v15's run
// dying. Everything else is byte-identical to v15:
//  (1) 2-deep pipelined polling (two 8-quad coherent batches alternating)
//  (2) vectorized publish via 4x4 shfl transpose (verified v11/v14)
// Epoch-in-data protocol unchanged (v9/v10); 0xAA poison = epoch 2 != 0.
__global__ void __launch_bounds__(NTHR, 1) lstm_persist_v16(
    const float* __restrict__ x,     // [512][64][256] fp32
    const float* __restrict__ h0,    // [64][512] fp32
    const float* __restrict__ c0,    // [64][512] fp32
    const float* __restrict__ w_ih,  // [2048][256] fp32
    const float* __restrict__ w_hh,  // [2048][512] fp32
    const float* __restrict__ b_ih,  // [2048] fp32
    const float* __restrict__ b_hh,  // [2048] fp32
    float* __restrict__ out,         // [512][64][512] ++ h_f ++ c_f (fp32)
    unsigned* __restrict__ hbuf)     // [2][64][512] packed u32 cells
{
  const int wg   = blockIdx.x;
  const int mh   = wg >> 5;        // batch quarter (group), 0..3
  const int ng   = wg & 31;        // hidden-col group (16 cols), 0..31
  const int b0   = mh * 16;
  const int j0   = ng * 16;
  const int tid  = threadIdx.x;
  const int wv   = tid >> 6;       // wave 0..3: owns cols j0+4*wv .. +3 (all 4 gates)
  const int lane = tid & 63;
  const int ln   = lane & 15;
  const int lq   = lane >> 4;
  const int gL   = ln >> 2;        // this lane's gate (B-frag row group)
  const int cL   = ln & 3;         // this lane's column within the wave's 4

  // LDS: weight lo-planes + h staging tile (row stride 516 u32 = b128 bank floor).
  __shared__ uintx4    wlo[4][24][64];      // 98304 B
  __shared__ unsigned  hstage[16][516];     // 33024 B  (total 131328)

  // ---- EMPIRICAL layout probe: local row of each acc slot (row = 4*lq + r) ----
  int row_l[4];
  {
    half8 ones, rowv;
#pragma unroll
    for (int i = 0; i < 8; ++i) { ones[i] = (_Float16)1.0f; rowv[i] = (_Float16)(float)ln; }
    floatx4 z = {0.f, 0.f, 0.f, 0.f};
    floatx4 p1 = __builtin_amdgcn_mfma_f32_16x16x32_f16(rowv, ones, z, 0, 0, 0);
#pragma unroll
    for (int r = 0; r < 4; ++r)
      row_l[r] = (int)(p1[r] * (1.0f / 32.0f) + 0.5f);
  }

  // ---- weights: hi-planes -> VGPRs; lo-planes -> LDS (own [wv][*][lane] slot) ----
  const int jg   = j0 + wv * 4 + cL;   // this lane's output column
  const int jb   = j0 + wv * 4;        // wave's column base
  const int grow = gL * NH + jg;       // row in w_ih/w_hh
  half8 whh_hi[16], wih_hi[8];
  {
#pragma unroll
    for (int s = 0; s < 16; ++s) {
      half8 lo;
      split8s(w_hh + (size_t)grow * NH + 32 * s + 8 * lq, whh_hi[s], lo);
      union { half8 h; uintx4 u; } cv; cv.h = lo;
      wlo[wv][s][lane] = cv.u;
    }
#pragma unroll
    for (int s = 0; s < 8; ++s) {
      half8 lo;
      split8s(w_ih + (size_t)grow * NI + 32 * s + 8 * lq, wih_hi[s], lo);
      union { half8 h; uintx4 u; } cv; cv.h = lo;
      wlo[wv][16 + s][lane] = cv.u;
    }
  }

  // ---- per-lane cell state: 4 cells (b = b0+row_l[r], col = jg) ----
  const float bias_i = b_ih[jg]          + b_hh[jg];
  const float bias_f = b_ih[NH + jg]     + b_hh[NH + jg];
  const float bias_g = b_ih[2 * NH + jg] + b_hh[2 * NH + jg];
  const float bias_o = b_ih[3 * NH + jg] + b_hh[3 * NH + jg];

  int   bg_r[4];
  float c_s[4];
#pragma unroll
  for (int r = 0; r < 4; ++r) {
    bg_r[r] = b0 + row_l[r];
    c_s[r]  = c0[bg_r[r] * NH + jg];
  }
  // row this lane stores after the 4x4 transpose (select, not runtime-indexed)
  const int brow_st = b0 + ((cL == 0) ? row_l[0] : (cL == 1) ? row_l[1]
                           : (cL == 2) ? row_l[2] : row_l[3]);

  const int PAR = NB * NH;

  // ---- publish packed h0 (epoch 0) into parity 0; no drain, no flag ----
  if (gL == 0) {
#pragma unroll
    for (int r = 0; r < 4; ++r)
      __hip_atomic_store(&hbuf[bg_r[r] * NH + jg], pack_cell_e(h0[bg_r[r] * NH + jg], 0u),
                         __ATOMIC_RELAXED, __HIP_MEMORY_SCOPE_AGENT);
  }

  const int arow = b0 + ln;           // A-fragment batch row
  const int srow = tid & 15;          // staging: batch row
  const int scb  = (tid >> 4) * 32;   // staging: col base (32 u32 = 8 quads/thread)

  for (int t = 0; t < NTS; ++t) {
    // ---- A) issue first stage batch immediately (flight hides under x-part) ----
    const unsigned* hb = hbuf + (t & 1) * PAR + (b0 + srow) * NH + scb;
    uintx4 hv[8];
#pragma unroll
    for (int q = 0; q < 8; ++q) hv[q] = load_cx4(hb + 4 * q);

    // ---- B) x-part: h-independent ----
    floatx4 acc_x   = {0.f, 0.f, 0.f, 0.f};
    floatx4 accl_x1 = {0.f, 0.f, 0.f, 0.f};
    floatx4 accl_x2 = {0.f, 0.f, 0.f, 0.f};
#pragma unroll
    for (int s = 0; s < 8; ++s) {
      half8 xh, xl;
      split8s(x + ((size_t)t * NB + arow) * NI + 32 * s + 8 * lq, xh, xl);
      union { uintx4 u; half8 h; } wl; wl.u = wlo[wv][16 + s][lane];
      acc_x   = __builtin_amdgcn_mfma_f32_16x16x32_f16(xh, wih_hi[s], acc_x,   0, 0, 0);
      accl_x1 = __builtin_amdgcn_mfma_f32_16x16x32_f16(xl, wih_hi[s], accl_x1, 0, 0, 0);
      accl_x2 = __builtin_amdgcn_mfma_f32_16x16x32_f16(xh, wl.h,      accl_x2, 0, 0, 0);
    }

    // ---- C) barrier: prior-step hstage readers done ----
    __syncthreads();

    // ---- D) 2-deep pipelined poll+stage; ALWAYS drain before exiting ----
    {
      const unsigned em = (unsigned)((t >> 1) & 3) << 16;
      uintx4 hw[8];
#pragma unroll
      for (int q = 0; q < 8; ++q) hw[q] = load_cx4(hb + 4 * q);   // batch 2

      unsigned pend = 0xFFu;
      for (;;) {
        // wait for the older batch (hv); newer batch (hw, 8 loads) stays in flight
        asm volatile("s_waitcnt vmcnt(8)" ::: "memory");
#pragma unroll
        for (int q = 0; q < 8; ++q) {
          if (pend & (1u << q)) {
            uintx4 v = hv[q];
            unsigned bad = ((v[0] ^ em) | (v[1] ^ em) | (v[2] ^ em) | (v[3] ^ em))
                           & 0x00030000u;
            if (!bad) {
              *(uintx4*)&hstage[srow][scb + 4 * q] = v;
              pend &= ~(1u << q);
            }
          }
        }
        if (__ballot(pend != 0u) == 0ull) break;
#pragma unroll
        for (int q = 0; q < 8; ++q) hv[q] = load_cx4(hb + 4 * q);  // reissue batch 1

        asm volatile("s_waitcnt vmcnt(8)" ::: "memory");
#pragma unroll
        for (int q = 0; q < 8; ++q) {
          if (pend & (1u << q)) {
            uintx4 v = hw[q];
            unsigned bad = ((v[0] ^ em) | (v[1] ^ em) | (v[2] ^ em) | (v[3] ^ em))
                           & 0x00030000u;
            if (!bad) {
              *(uintx4*)&hstage[srow][scb + 4 * q] = v;
              pend &= ~(1u << q);
            }
          }
        }
        if (__ballot(pend != 0u) == 0ull) break;
#pragma unroll
        for (int q = 0; q < 8; ++q) hw[q] = load_cx4(hb + 4 * q);  // reissue batch 2
      }
      // Drain the still-in-flight batch BEFORE the compiler can reuse hv/hw
      // registers (late-completion clobber hazard; v10 never had in-flight
      // loads at loop exit, v15 did - this is the v16 fix).
      asm volatile("s_waitcnt vmcnt(0)" ::: "memory");
    }
    __syncthreads();     // all stage writes visible to all waves

    // ---- E) h-part: gates += h_t*Whh^T; 6 independent 8-deep MFMA chains ----
    floatx4 acc_h  = {0.f, 0.f, 0.f, 0.f}, acc_h2  = {0.f, 0.f, 0.f, 0.f};
    floatx4 accl_a = {0.f, 0.f, 0.f, 0.f}, accl_a2 = {0.f, 0.f, 0.f, 0.f};
    floatx4 accl_b = {0.f, 0.f, 0.f, 0.f}, accl_b2 = {0.f, 0.f, 0.f, 0.f};
#pragma unroll
    for (int s = 0; s < 16; ++s) {
      const uintx4* hp = (const uintx4*)&hstage[ln][32 * s + 8 * lq];
      uintx4 hA = hp[0], hB = hp[1];
      union { unsigned u[4]; half8 h; } Ah, Al;
      Ah.u[0] = __builtin_amdgcn_perm(hA[1], hA[0], 0x05040100u);
      Al.u[0] = __builtin_amdgcn_perm(hA[1], hA[0], 0x07060302u);
      Ah.u[1] = __builtin_amdgcn_perm(hA[3], hA[2], 0x05040100u);
      Al.u[1] = __builtin_amdgcn_perm(hA[3], hA[2], 0x07060302u);
      Ah.u[2] = __builtin_amdgcn_perm(hB[1], hB[0], 0x05040100u);
      Al.u[2] = __builtin_amdgcn_perm(hB[1], hB[0], 0x07060302u);
      Ah.u[3] = __builtin_amdgcn_perm(hB[3], hB[2], 0x05040100u);
      Al.u[3] = __builtin_amdgcn_perm(hB[3], hB[2], 0x07060302u);
      union { uintx4 u; half8 h; } wl; wl.u = wlo[wv][s][lane];
      if (s < 8) {
        acc_h  = __builtin_amdgcn_mfma_f32_16x16x32_f16(Ah.h, whh_hi[s], acc_h,  0, 0, 0);
        accl_a = __builtin_amdgcn_mfma_f32_16x16x32_f16(Al.h, whh_hi[s], accl_a, 0, 0, 0);
        accl_b = __builtin_amdgcn_mfma_f32_16x16x32_f16(Ah.h, wl.h,      accl_b, 0, 0, 0);
      } else {
        acc_h2  = __builtin_amdgcn_mfma_f32_16x16x32_f16(Ah.h, whh_hi[s], acc_h2,  0, 0, 0);
        accl_a2 = __builtin_amdgcn_mfma_f32_16x16x32_f16(Al.h, whh_hi[s], accl_a2, 0, 0, 0);
        accl_b2 = __builtin_amdgcn_mfma_f32_16x16x32_f16(Ah.h, wl.h,      accl_b2, 0, 0, 0);
      }
    }

    // ---- F) pointwise LSTM cell: gather i/f/g/o across the 4 gate lane-groups ----
    const int par1 = ((t + 1) & 1) * PAR;
    const unsigned ep1 = (unsigned)(((t + 1) >> 1) & 3);
    float hn[4];
#pragma unroll
    for (int r = 0; r < 4; ++r) {
      float hi_s = acc_x[r] + acc_h[r] + acc_h2[r];
      float lo_s = accl_x1[r] + accl_x2[r] + accl_a[r] + accl_a2[r]
                 + accl_b[r] + accl_b2[r];
      float pre = hi_s + lo_s * LOINV;
      float pb = __shfl_xor(pre, 4);   // value from gate gL^1
      float pc = __shfl_xor(pre, 8);   // value from gate gL^2
      float pd = __shfl_xor(pb, 8);    // value from gate gL^3
      const bool g1 = (gL & 1), g2 = (gL & 2) != 0;
      float xi = g2 ? (g1 ? pd : pc) : (g1 ? pb : pre);
      float xf = g2 ? (g1 ? pc : pd) : (g1 ? pre : pb);
      float xg = g2 ? (g1 ? pb : pre) : (g1 ? pd : pc);
      float xo = g2 ? (g1 ? pre : pb) : (g1 ? pc : pd);
      xi += bias_i; xf += bias_f; xg += bias_g; xo += bias_o;
      float ig = 1.f / (1.f + __expf(-xi));
      float fg = 1.f / (1.f + __expf(-xf));
      float gg = 2.f / (1.f + __expf(-2.f * xg)) - 1.f;   // tanh
      float og = 1.f / (1.f + __expf(-xo));
      c_s[r] = fg * c_s[r] + ig * gg;
      float tc = 2.f / (1.f + __expf(-2.f * c_s[r])) - 1.f;  // tanh(c)
      hn[r] = og * tc;
    }

    if (t < NTS - 1) {
      // ---- G) 4x4 lane transpose (xor 1 then xor 2): lane cL ends up with row
      //      bg_r[cL], cols jb..jb+3 -> ONE dwordx4 publish (verified v11/v14) ----
      const bool c0b = (lane & 1), c1b = (lane & 2) != 0;
      float a0 = __shfl_xor(hn[1], 1), a1 = __shfl_xor(hn[0], 1);
      float a2 = __shfl_xor(hn[3], 1), a3 = __shfl_xor(hn[2], 1);
      float v10 = c0b ? a0 : hn[0], v11 = c0b ? hn[1] : a1;
      float v12 = c0b ? a2 : hn[2], v13 = c0b ? hn[3] : a3;
      float b0v = __shfl_xor(v12, 2), b1v = __shfl_xor(v13, 2);
      float b2v = __shfl_xor(v10, 2), b3v = __shfl_xor(v11, 2);
      float T0 = c1b ? b0v : v10, T1 = c1b ? b1v : v11;
      float T2 = c1b ? v12 : b2v, T3 = c1b ? v13 : b3v;

      if (gL == 0) {
        uintx4 pk;
        pk[0] = pack_cell_e(T0, ep1);
        pk[1] = pack_cell_e(T1, ep1);
        pk[2] = pack_cell_e(T2, ep1);
        pk[3] = pack_cell_e(T3, ep1);
        store_cx4(&hbuf[par1 + brow_st * NH + jb], pk);     // publish FIRST
        floatx4 ov = {T0, T1, T2, T3};
        *(floatx4*)&out[((size_t)t * NB + brow_st) * NH + jb] = ov;
      }
    } else {
      if (gL == 0) {
        const size_t hf_off = (size_t)NTS * NB * NH;
#pragma unroll
        for (int r = 0; r < 4; ++r) {
          out[((size_t)t * NB + bg_r[r]) * NH + jg] = hn[r];
          out[hf_off + bg_r[r] * NH + jg] = hn[r];                          // h_f
          out[hf_off + (size_t)NB * NH + bg_r[r] * NH + jg] = c_s[r];       // c_f
        }
      }
    }
  }
}

extern "C" void kernel_launch(void* const* d_in, const int* in_sizes, int n_in,
                              void* d_out, int out_size, void* d_ws, size_t ws_size,
                              hipStream_t stream) {
  const float* x    = (const float*)d_in[0];
  const float* h0   = (const float*)d_in[1];
  const float* c0   = (const float*)d_in[2];
  const float* w_ih = (const float*)d_in[3];
  const float* w_hh = (const float*)d_in[4];
  const float* b_ih = (const float*)d_in[5];
  const float* b_hh = (const float*)d_in[6];
  float* out = (float*)d_out;
  unsigned* hbuf = (unsigned*)d_ws;   // 2*64*512 u32 = 256 KB

  // 0xAA poison decodes to epoch 2 != E(0)=0: no workspace init needed.
  hipLaunchKernelGGL(lstm_persist_v16, dim3(NWG), dim3(NTHR), 0, stream,
                     x, h0, c0, w_ih, w_hh, b_ih, b_hh, out, hbuf);
}

// Round 12
// 4863.942 us; speedup vs baseline: 1.3024x; 1.0095x over previous
//
#include <hip/hip_runtime.h>
#include <hip/hip_bf16.h>

typedef __attribute__((ext_vector_type(8))) _Float16 half8;
typedef __attribute__((ext_vector_type(4))) float floatx4;
typedef __attribute__((ext_vector_type(4))) unsigned uintx4;

#define NTS 512    // timesteps
#define NB  64     // batch
#define NI  256    // input dim
#define NH  512    // hidden
#define NWG 64     // 4 batch groups x 16 col groups (32 cols each)
#define NTHR 256   // 4 waves

#define LOSCALE 4096.0f
#define LOINV   (1.0f / 4096.0f)

// fp32 -> (hi f16, lo f16 scaled by 2^12)
static __device__ __forceinline__ void split8s(const float* p, half8& hi, half8& lo) {
  float4 a = *(const float4*)p;
  float4 b = *(const float4*)(p + 4);
  float v[8] = {a.x, a.y, a.z, a.w, b.x, b.y, b.z, b.w};
#pragma unroll
  for (int i = 0; i < 8; ++i) {
    _Float16 h = (_Float16)v[i];
    hi[i] = h;
    lo[i] = (_Float16)((v[i] - (float)h) * LOSCALE);
  }
}

// pack one h cell with a 2-bit epoch stolen from the lo-plane mantissa LSBs:
// bits[15:0] = hi(f16); bits[31:18] = lo[15:2]; bits[17:16] = epoch.
static __device__ __forceinline__ unsigned pack_cell_e(float v, unsigned ep) {
  _Float16 h = (_Float16)v;
  _Float16 l = (_Float16)((v - (float)h) * LOSCALE);
  union { _Float16 f; unsigned short s; } uh, ul;
  uh.f = h; ul.f = l;
  unsigned lo = ((unsigned)ul.s & 0xFFFCu) | (ep & 3u);
  return (lo << 16) | (unsigned)uh.s;
}

// Coherent 16B load/store: sc0+sc1 = at the device coherence point.
static __device__ __forceinline__ uintx4 load_cx4(const unsigned* p) {
  uintx4 r;
  asm volatile("global_load_dwordx4 %0, %1, off sc0 sc1"
               : "=v"(r)
               : "v"((unsigned long long)p)
               : "memory");
  return r;
}
static __device__ __forceinline__ void store_cx4(unsigned* p, uintx4 v) {
  asm volatile("global_store_dwordx4 %0, %1, off sc0 sc1"
               :: "v"((unsigned long long)p), "v"(v)
               : "memory");
}

// Persistent LSTM v17: HALVE coherent read transactions without changing the
// wave shape. v16 proved the fabric is service-rate-bound (traffic +62% ->
// time +65%, linear); v10's 128 WGs each re-read the same group h-tile. v17:
// 64 WGs x 4 waves (proven regalloc regime, 1 wave/SIMD -> ~450 VGPR no-spill
// per m08), each WG = 16 rows x 32 cols (2 col-quads per wave). Stage reads:
// 131K dwordx4/step (half of v10); sync partners 16 (half); publish via 4x4
// shfl transpose = 8.2K dwordx4 stores (quarter of v10's 32.8K dwords).
// Weights: cq-a hi+lo and cq-b hi in VGPRs (~288 regs); cq-b lo-planes in LDS
// (exactly v10's wlo footprint). Poll loop = v10's proven predicated vmcnt(0)
// rounds (v16's pipelined variant REGRESSED - abandoned).
// Epoch-in-data protocol unchanged (v9/v10): parity double-buffer, 2-bit epoch
// per cell, 0xAA poison = epoch 2 != E(0)=0 -> no workspace init.
__global__ void __launch_bounds__(NTHR, 1) lstm_persist_v17(
    const float* __restrict__ x,     // [512][64][256] fp32
    const float* __restrict__ h0,    // [64][512] fp32
    const float* __restrict__ c0,    // [64][512] fp32
    const float* __restrict__ w_ih,  // [2048][256] fp32
    const float* __restrict__ w_hh,  // [2048][512] fp32
    const float* __restrict__ b_ih,  // [2048] fp32
    const float* __restrict__ b_hh,  // [2048] fp32
    float* __restrict__ out,         // [512][64][512] ++ h_f ++ c_f (fp32)
    unsigned* __restrict__ hbuf)     // [2][64][512] packed u32 cells
{
  const int wg   = blockIdx.x;
  const int mh   = wg >> 4;        // batch quarter (group), 0..3
  const int ng   = wg & 15;        // hidden-col group (32 cols), 0..15
  const int b0   = mh * 16;
  const int j0   = ng * 32;
  const int tid  = threadIdx.x;
  const int wv   = tid >> 6;       // wave 0..3: owns cols j0+8*wv .. +7 (all 4 gates)
  const int lane = tid & 63;
  const int ln   = lane & 15;
  const int lq   = lane >> 4;
  const int gL   = ln >> 2;        // this lane's gate (B-frag row group)
  const int cL   = ln & 3;         // this lane's column within a col-quad

  // LDS: cq-b lo-planes (slots 0-15 whh_lo_b, 16-23 wih_lo_b) + h staging tile
  // (row stride 516 u32 = b128 bank floor). Total 131328 B — identical to v10.
  __shared__ uintx4    wlo[4][24][64];      // 98304 B
  __shared__ unsigned  hstage[16][516];     // 33024 B

  // ---- EMPIRICAL layout probe: local row of each acc slot (row = 4*lq + r) ----
  int row_l[4];
  {
    half8 ones, rowv;
#pragma unroll
    for (int i = 0; i < 8; ++i) { ones[i] = (_Float16)1.0f; rowv[i] = (_Float16)(float)ln; }
    floatx4 z = {0.f, 0.f, 0.f, 0.f};
    floatx4 p1 = __builtin_amdgcn_mfma_f32_16x16x32_f16(rowv, ones, z, 0, 0, 0);
#pragma unroll
    for (int r = 0; r < 4; ++r)
      row_l[r] = (int)(p1[r] * (1.0f / 32.0f) + 0.5f);
  }

  // ---- weights: two col-quads per wave ----
  const int jb    = j0 + wv * 8;       // wave's col base (8 cols)
  const int jga   = jb + cL;           // cq-a column
  const int jgb   = jb + 4 + cL;       // cq-b column
  const int growa = gL * NH + jga;
  const int growb = gL * NH + jgb;
  half8 whh_hi_a[16], whh_hi_b[16], whh_lo_a[16];
  half8 wih_hi_a[8],  wih_hi_b[8],  wih_lo_a[8];
  {
#pragma unroll
    for (int s = 0; s < 16; ++s) {
      split8s(w_hh + (size_t)growa * NH + 32 * s + 8 * lq, whh_hi_a[s], whh_lo_a[s]);
      half8 lob;
      split8s(w_hh + (size_t)growb * NH + 32 * s + 8 * lq, whh_hi_b[s], lob);
      union { half8 h; uintx4 u; } cv; cv.h = lob;
      wlo[wv][s][lane] = cv.u;
    }
#pragma unroll
    for (int s = 0; s < 8; ++s) {
      split8s(w_ih + (size_t)growa * NI + 32 * s + 8 * lq, wih_hi_a[s], wih_lo_a[s]);
      half8 lob;
      split8s(w_ih + (size_t)growb * NI + 32 * s + 8 * lq, wih_hi_b[s], lob);
      union { half8 h; uintx4 u; } cv; cv.h = lob;
      wlo[wv][16 + s][lane] = cv.u;
    }
  }

  // ---- per-lane cell state: 4 cells per cq ----
  const float bi_a = b_ih[jga]          + b_hh[jga];
  const float bf_a = b_ih[NH + jga]     + b_hh[NH + jga];
  const float bg_a = b_ih[2 * NH + jga] + b_hh[2 * NH + jga];
  const float bo_a = b_ih[3 * NH + jga] + b_hh[3 * NH + jga];
  const float bi_b = b_ih[jgb]          + b_hh[jgb];
  const float bf_b = b_ih[NH + jgb]     + b_hh[NH + jgb];
  const float bg_b = b_ih[2 * NH + jgb] + b_hh[2 * NH + jgb];
  const float bo_b = b_ih[3 * NH + jgb] + b_hh[3 * NH + jgb];

  int   bg_r[4];
  float cs_a[4], cs_b[4];
#pragma unroll
  for (int r = 0; r < 4; ++r) {
    bg_r[r] = b0 + row_l[r];
    cs_a[r] = c0[bg_r[r] * NH + jga];
    cs_b[r] = c0[bg_r[r] * NH + jgb];
  }
  // row this lane stores after the 4x4 transpose (select, not runtime-indexed)
  const int brow_st = b0 + ((cL == 0) ? row_l[0] : (cL == 1) ? row_l[1]
                           : (cL == 2) ? row_l[2] : row_l[3]);

  const int PAR = NB * NH;

  // ---- publish packed h0 (epoch 0) into parity 0 ----
  if (gL == 0) {
#pragma unroll
    for (int r = 0; r < 4; ++r) {
      __hip_atomic_store(&hbuf[bg_r[r] * NH + jga], pack_cell_e(h0[bg_r[r] * NH + jga], 0u),
                         __ATOMIC_RELAXED, __HIP_MEMORY_SCOPE_AGENT);
      __hip_atomic_store(&hbuf[bg_r[r] * NH + jgb], pack_cell_e(h0[bg_r[r] * NH + jgb], 0u),
                         __ATOMIC_RELAXED, __HIP_MEMORY_SCOPE_AGENT);
    }
  }

  const int arow = b0 + ln;           // A-fragment batch row
  const int srow = tid & 15;          // staging: batch row
  const int scb  = (tid >> 4) * 32;   // staging: col base (32 u32 = 8 quads/thread)

  for (int t = 0; t < NTS; ++t) {
    // ---- A) issue stage loads immediately (flight hides under x-part) ----
    const unsigned* hb = hbuf + (t & 1) * PAR + (b0 + srow) * NH + scb;
    uintx4 hv[8];
#pragma unroll
    for (int q = 0; q < 8; ++q) hv[q] = load_cx4(hb + 4 * q);

    // ---- B) x-part: h-independent; 6 acc chains (x folds into h accs) ----
    floatx4 acc_a  = {0.f, 0.f, 0.f, 0.f}, acc_b  = {0.f, 0.f, 0.f, 0.f};
    floatx4 acl_a1 = {0.f, 0.f, 0.f, 0.f}, acl_b1 = {0.f, 0.f, 0.f, 0.f};
    floatx4 acl_a2 = {0.f, 0.f, 0.f, 0.f}, acl_b2 = {0.f, 0.f, 0.f, 0.f};
#pragma unroll
    for (int s = 0; s < 8; ++s) {
      half8 xh, xl;
      split8s(x + ((size_t)t * NB + arow) * NI + 32 * s + 8 * lq, xh, xl);
      union { uintx4 u; half8 h; } wlb; wlb.u = wlo[wv][16 + s][lane];
      acc_a  = __builtin_amdgcn_mfma_f32_16x16x32_f16(xh, wih_hi_a[s], acc_a,  0, 0, 0);
      acl_a1 = __builtin_amdgcn_mfma_f32_16x16x32_f16(xl, wih_hi_a[s], acl_a1, 0, 0, 0);
      acl_a2 = __builtin_amdgcn_mfma_f32_16x16x32_f16(xh, wih_lo_a[s], acl_a2, 0, 0, 0);
      acc_b  = __builtin_amdgcn_mfma_f32_16x16x32_f16(xh, wih_hi_b[s], acc_b,  0, 0, 0);
      acl_b1 = __builtin_amdgcn_mfma_f32_16x16x32_f16(xl, wih_hi_b[s], acl_b1, 0, 0, 0);
      acl_b2 = __builtin_amdgcn_mfma_f32_16x16x32_f16(xh, wlb.h,       acl_b2, 0, 0, 0);
    }

    // ---- C) barrier: prior-step hstage readers done ----
    __syncthreads();

    // ---- D) poll+stage: v10's proven predicated vmcnt(0) rounds ----
    {
      const unsigned em = (unsigned)((t >> 1) & 3) << 16;
      unsigned pend = 0xFFu;
      for (;;) {
        asm volatile("s_waitcnt vmcnt(0)" ::: "memory");
#pragma unroll
        for (int q = 0; q < 8; ++q) {
          if (pend & (1u << q)) {
            uintx4 v = hv[q];
            unsigned bad = ((v[0] ^ em) | (v[1] ^ em) | (v[2] ^ em) | (v[3] ^ em))
                           & 0x00030000u;
            if (!bad) {
              *(uintx4*)&hstage[srow][scb + 4 * q] = v;
              pend &= ~(1u << q);
            }
          }
        }
        if (__ballot(pend != 0u) == 0ull) break;
#pragma unroll
        for (int q = 0; q < 8; ++q)
          if (pend & (1u << q)) hv[q] = load_cx4(hb + 4 * q);
      }
    }
    __syncthreads();     // all stage writes visible to all waves

    // ---- E) h-part: A-fragments shared across both col-quads ----
#pragma unroll
    for (int s = 0; s < 16; ++s) {
      const uintx4* hp = (const uintx4*)&hstage[ln][32 * s + 8 * lq];
      uintx4 hA = hp[0], hB = hp[1];
      union { unsigned u[4]; half8 h; } Ah, Al;
      Ah.u[0] = __builtin_amdgcn_perm(hA[1], hA[0], 0x05040100u);
      Al.u[0] = __builtin_amdgcn_perm(hA[1], hA[0], 0x07060302u);
      Ah.u[1] = __builtin_amdgcn_perm(hA[3], hA[2], 0x05040100u);
      Al.u[1] = __builtin_amdgcn_perm(hA[3], hA[2], 0x07060302u);
      Ah.u[2] = __builtin_amdgcn_perm(hB[1], hB[0], 0x05040100u);
      Al.u[2] = __builtin_amdgcn_perm(hB[1], hB[0], 0x07060302u);
      Ah.u[3] = __builtin_amdgcn_perm(hB[3], hB[2], 0x05040100u);
      Al.u[3] = __builtin_amdgcn_perm(hB[3], hB[2], 0x07060302u);
      union { uintx4 u; half8 h; } wlb; wlb.u = wlo[wv][s][lane];
      acc_a  = __builtin_amdgcn_mfma_f32_16x16x32_f16(Ah.h, whh_hi_a[s], acc_a,  0, 0, 0);
      acl_a1 = __builtin_amdgcn_mfma_f32_16x16x32_f16(Al.h, whh_hi_a[s], acl_a1, 0, 0, 0);
      acl_a2 = __builtin_amdgcn_mfma_f32_16x16x32_f16(Ah.h, whh_lo_a[s], acl_a2, 0, 0, 0);
      acc_b  = __builtin_amdgcn_mfma_f32_16x16x32_f16(Ah.h, whh_hi_b[s], acc_b,  0, 0, 0);
      acl_b1 = __builtin_amdgcn_mfma_f32_16x16x32_f16(Al.h, whh_hi_b[s], acl_b1, 0, 0, 0);
      acl_b2 = __builtin_amdgcn_mfma_f32_16x16x32_f16(Ah.h, wlb.h,       acl_b2, 0, 0, 0);
    }

    // ---- F) pointwise LSTM cell, per col-quad ----
    const int par1 = ((t + 1) & 1) * PAR;
    const unsigned ep1 = (unsigned)(((t + 1) >> 1) & 3);
    const bool g1 = (gL & 1), g2 = (gL & 2) != 0;
    float hn_a[4], hn_b[4];
#pragma unroll
    for (int r = 0; r < 4; ++r) {
      // cq-a
      {
        float pre = (acc_a[r]) + (acl_a1[r] + acl_a2[r]) * LOINV;
        float pb = __shfl_xor(pre, 4);
        float pc = __shfl_xor(pre, 8);
        float pd = __shfl_xor(pb, 8);
        float xi = g2 ? (g1 ? pd : pc) : (g1 ? pb : pre);
        float xf = g2 ? (g1 ? pc : pd) : (g1 ? pre : pb);
        float xg = g2 ? (g1 ? pb : pre) : (g1 ? pd : pc);
        float xo = g2 ? (g1 ? pre : pb) : (g1 ? pc : pd);
        xi += bi_a; xf += bf_a; xg += bg_a; xo += bo_a;
        float ig = 1.f / (1.f + __expf(-xi));
        float fg = 1.f / (1.f + __expf(-xf));
        float gg = 2.f / (1.f + __expf(-2.f * xg)) - 1.f;
        float og = 1.f / (1.f + __expf(-xo));
        cs_a[r] = fg * cs_a[r] + ig * gg;
        float tc = 2.f / (1.f + __expf(-2.f * cs_a[r])) - 1.f;
        hn_a[r] = og * tc;
      }
      // cq-b
      {
        float pre = (acc_b[r]) + (acl_b1[r] + acl_b2[r]) * LOINV;
        float pb = __shfl_xor(pre, 4);
        float pc = __shfl_xor(pre, 8);
        float pd = __shfl_xor(pb, 8);
        float xi = g2 ? (g1 ? pd : pc) : (g1 ? pb : pre);
        float xf = g2 ? (g1 ? pc : pd) : (g1 ? pre : pb);
        float xg = g2 ? (g1 ? pb : pre) : (g1 ? pd : pc);
        float xo = g2 ? (g1 ? pre : pb) : (g1 ? pc : pd);
        xi += bi_b; xf += bf_b; xg += bg_b; xo += bo_b;
        float ig = 1.f / (1.f + __expf(-xi));
        float fg = 1.f / (1.f + __expf(-xf));
        float gg = 2.f / (1.f + __expf(-2.f * xg)) - 1.f;
        float og = 1.f / (1.f + __expf(-xo));
        cs_b[r] = fg * cs_b[r] + ig * gg;
        float tc = 2.f / (1.f + __expf(-2.f * cs_b[r])) - 1.f;
        hn_b[r] = og * tc;
      }
    }

    if (t < NTS - 1) {
      // ---- G) 4x4 lane transpose per cq -> ONE dwordx4 publish each ----
      const bool c0b = (lane & 1), c1b = (lane & 2) != 0;
      // cq-a transpose
      float a0 = __shfl_xor(hn_a[1], 1), a1 = __shfl_xor(hn_a[0], 1);
      float a2 = __shfl_xor(hn_a[3], 1), a3 = __shfl_xor(hn_a[2], 1);
      float v10 = c0b ? a0 : hn_a[0], v11 = c0b ? hn_a[1] : a1;
      float v12 = c0b ? a2 : hn_a[2], v13 = c0b ? hn_a[3] : a3;
      float b0v = __shfl_xor(v12, 2), b1v = __shfl_xor(v13, 2);
      float b2v = __shfl_xor(v10, 2), b3v = __shfl_xor(v11, 2);
      float TA0 = c1b ? b0v : v10, TA1 = c1b ? b1v : v11;
      float TA2 = c1b ? v12 : b2v, TA3 = c1b ? v13 : b3v;
      // cq-b transpose
      float d0 = __shfl_xor(hn_b[1], 1), d1 = __shfl_xor(hn_b[0], 1);
      float d2 = __shfl_xor(hn_b[3], 1), d3 = __shfl_xor(hn_b[2], 1);
      float w10 = c0b ? d0 : hn_b[0], w11 = c0b ? hn_b[1] : d1;
      float w12 = c0b ? d2 : hn_b[2], w13 = c0b ? hn_b[3] : d3;
      float e0v = __shfl_xor(w12, 2), e1v = __shfl_xor(w13, 2);
      float e2v = __shfl_xor(w10, 2), e3v = __shfl_xor(w11, 2);
      float TB0 = c1b ? e0v : w10, TB1 = c1b ? e1v : w11;
      float TB2 = c1b ? w12 : e2v, TB3 = c1b ? w13 : e3v;

      if (gL == 0) {
        uintx4 pa, pbq;
        pa[0] = pack_cell_e(TA0, ep1); pa[1] = pack_cell_e(TA1, ep1);
        pa[2] = pack_cell_e(TA2, ep1); pa[3] = pack_cell_e(TA3, ep1);
        pbq[0] = pack_cell_e(TB0, ep1); pbq[1] = pack_cell_e(TB1, ep1);
        pbq[2] = pack_cell_e(TB2, ep1); pbq[3] = pack_cell_e(TB3, ep1);
        store_cx4(&hbuf[par1 + brow_st * NH + jb],     pa);   // publish FIRST
        store_cx4(&hbuf[par1 + brow_st * NH + jb + 4], pbq);
        floatx4 oa = {TA0, TA1, TA2, TA3};
        floatx4 ob = {TB0, TB1, TB2, TB3};
        *(floatx4*)&out[((size_t)t * NB + brow_st) * NH + jb]     = oa;
        *(floatx4*)&out[((size_t)t * NB + brow_st) * NH + jb + 4] = ob;
      }
    } else {
      if (gL == 0) {
        const size_t hf_off = (size_t)NTS * NB * NH;
#pragma unroll
        for (int r = 0; r < 4; ++r) {
          out[((size_t)t * NB + bg_r[r]) * NH + jga] = hn_a[r];
          out[((size_t)t * NB + bg_r[r]) * NH + jgb] = hn_b[r];
          out[hf_off + bg_r[r] * NH + jga] = hn_a[r];                        // h_f
          out[hf_off + bg_r[r] * NH + jgb] = hn_b[r];
          out[hf_off + (size_t)NB * NH + bg_r[r] * NH + jga] = cs_a[r];      // c_f
          out[hf_off + (size_t)NB * NH + bg_r[r] * NH + jgb] = cs_b[r];
        }
      }
    }
  }
}

extern "C" void kernel_launch(void* const* d_in, const int* in_sizes, int n_in,
                              void* d_out, int out_size, void* d_ws, size_t ws_size,
                              hipStream_t stream) {
  const float* x    = (const float*)d_in[0];
  const float* h0   = (const float*)d_in[1];
  const float* c0   = (const float*)d_in[2];
  const float* w_ih = (const float*)d_in[3];
  const float* w_hh = (const float*)d_in[4];
  const float* b_ih = (const float*)d_in[5];
  const float* b_hh = (const float*)d_in[6];
  float* out = (float*)d_out;
  unsigned* hbuf = (unsigned*)d_ws;   // 2*64*512 u32 = 256 KB

  // 0xAA poison decodes to epoch 2 != E(0)=0: no workspace init needed.
  hipLaunchKernelGGL(lstm_persist_v17, dim3(NWG), dim3(NTHR), 0, stream,
                     x, h0, c0, w_ih, w_hh, b_ih, b_hh, out, hbuf);
}